// Round 1
// baseline (253.452 us; speedup 1.0000x reference)
//
#include <hip/hip_runtime.h>
#include <math.h>

// Cascaded biquad bandpass (lowpass 3400 Hz -> highpass 300 Hz), torchaudio
// semantics: DF2T recurrence, clamp [-1,1] after each stage (states use
// unclamped y). Parallelized over time via truncated-IIR warmup chunks:
// slowest pole |p|=0.9201 -> W=128 warmup gives ~2e-5 state error, far
// below the 6.8e-3 threshold.

#define NT   256                 // threads per block
#define LCH  64                  // output samples per thread
#define WU   128                 // warmup samples per thread
#define SPAN (NT * LCH)          // 16384 samples per block
#define STAGE (SPAN + WU)        // 16512 floats staged in LDS
#define T_LEN 480000

// pad-every-64 swizzle: lane stride becomes 65 floats -> 2-way bank access (free)
__device__ __forceinline__ int sw(int i) { return i + (i >> 6); }
#define LDS_FLOATS (STAGE + (STAGE >> 6) + 1)

__global__ __launch_bounds__(NT, 2)
void bandpass_kernel(const float* __restrict__ in, float* __restrict__ out,
                     float lb0, float lb1, float lb2, float la1, float la2,
                     float hb0, float hb1, float hb2, float ha1, float ha2) {
    __shared__ float lds[LDS_FLOATS];
    const int tile = blockIdx.x;
    const int seq  = blockIdx.y;
    const int tid  = threadIdx.x;
    const long tile_start = (long)tile * SPAN;
    const float* __restrict__ src = in  + (long)seq * T_LEN;
    float*       __restrict__ dst = out + (long)seq * T_LEN;

    // ---- stage [tile_start - WU, tile_start + SPAN) into LDS, zero-fill OOB
    for (int k = tid * 4; k < STAGE; k += NT * 4) {
        long g = tile_start - WU + k;
        float4 v;
        if (g >= 0 && g + 3 < T_LEN) {
            v = *(const float4*)(src + g);
        } else {
            v.x = (g + 0 >= 0 && g + 0 < T_LEN) ? src[g + 0] : 0.f;
            v.y = (g + 1 >= 0 && g + 1 < T_LEN) ? src[g + 1] : 0.f;
            v.z = (g + 2 >= 0 && g + 2 < T_LEN) ? src[g + 2] : 0.f;
            v.w = (g + 3 >= 0 && g + 3 < T_LEN) ? src[g + 3] : 0.f;
        }
        lds[sw(k + 0)] = v.x;
        lds[sw(k + 1)] = v.y;
        lds[sw(k + 2)] = v.z;
        lds[sw(k + 3)] = v.w;
    }
    __syncthreads();

    float s1a = 0.f, s2a = 0.f, s1b = 0.f, s2b = 0.f;
    const int base = tid * LCH;  // linear LDS index of this thread's warmup start

    // ---- warmup: WU samples, establishes filter state, no output
    #pragma unroll 4
    for (int s = 0; s < WU; ++s) {
        float x  = lds[sw(base + s)];
        float y1 = fmaf(lb0, x, s1a);
        s1a = fmaf(lb1, x, fmaf(-la1, y1, s2a));
        s2a = fmaf(lb2, x, -la2 * y1);
        float x2 = fminf(fmaxf(y1, -1.f), 1.f);
        float y2 = fmaf(hb0, x2, s1b);
        s1b = fmaf(hb1, x2, fmaf(-ha1, y2, s2b));
        s2b = fmaf(hb2, x2, -ha2 * y2);
    }
    __syncthreads();  // all cross-thread warmup reads done before in-place writes

    // ---- main: LCH samples, overwrite input with output in LDS (own chunk only)
    #pragma unroll 4
    for (int s = 0; s < LCH; ++s) {
        int idx  = sw(base + WU + s);
        float x  = lds[idx];
        float y1 = fmaf(lb0, x, s1a);
        s1a = fmaf(lb1, x, fmaf(-la1, y1, s2a));
        s2a = fmaf(lb2, x, -la2 * y1);
        float x2 = fminf(fmaxf(y1, -1.f), 1.f);
        float y2 = fmaf(hb0, x2, s1b);
        s1b = fmaf(hb1, x2, fmaf(-ha1, y2, s2b));
        s2b = fmaf(hb2, x2, -ha2 * y2);
        lds[idx] = fminf(fmaxf(y2, -1.f), 1.f);
    }
    __syncthreads();

    // ---- coalesced writeback of SPAN outputs
    for (int k = tid * 4; k < SPAN; k += NT * 4) {
        long g = tile_start + k;
        if (g + 3 < T_LEN) {
            float4 v;
            v.x = lds[sw(WU + k + 0)];
            v.y = lds[sw(WU + k + 1)];
            v.z = lds[sw(WU + k + 2)];
            v.w = lds[sw(WU + k + 3)];
            *(float4*)(dst + g) = v;
        } else if (g < T_LEN) {
            for (int j = 0; j < 4 && g + j < T_LEN; ++j)
                dst[g + j] = lds[sw(WU + k + j)];
        }
    }
}

static void biquad_coeffs(double cutoff, double sr, bool highpass, float* c) {
    const double Q  = 0.7071067811865476;
    const double w0 = 2.0 * M_PI * cutoff / sr;
    const double al = sin(w0) / (2.0 * Q);
    const double cw = cos(w0);
    double b0, b1, b2;
    if (highpass) { b0 = (1.0 + cw) / 2.0; b1 = -(1.0 + cw); b2 = b0; }
    else          { b0 = (1.0 - cw) / 2.0; b1 =  (1.0 - cw); b2 = b0; }
    const double a0 = 1.0 + al;
    const double a1 = -2.0 * cw;
    const double a2 = 1.0 - al;
    c[0] = (float)(b0 / a0);
    c[1] = (float)(b1 / a0);
    c[2] = (float)(b2 / a0);
    c[3] = (float)(a1 / a0);
    c[4] = (float)(a2 / a0);
}

extern "C" void kernel_launch(void* const* d_in, const int* in_sizes, int n_in,
                              void* d_out, int out_size, void* d_ws, size_t ws_size,
                              hipStream_t stream) {
    const float* in  = (const float*)d_in[0];
    float*       out = (float*)d_out;

    float lp[5], hp[5];
    biquad_coeffs(3400.0, 16000.0, false, lp);  // lowpass at max cutoff
    biquad_coeffs(300.0, 16000.0, true, hp);    // highpass at min cutoff

    const int n_seq  = in_sizes[0] / T_LEN;     // 32*2 = 64
    const int n_tile = (T_LEN + SPAN - 1) / SPAN;  // 30

    dim3 grid(n_tile, n_seq);
    bandpass_kernel<<<grid, NT, 0, stream>>>(
        in, out,
        lp[0], lp[1], lp[2], lp[3], lp[4],
        hp[0], hp[1], hp[2], hp[3], hp[4]);
}

// Round 2
// 234.166 us; speedup vs baseline: 1.0824x; 1.0824x over previous
//
#include <hip/hip_runtime.h>
#include <math.h>

// Cascaded biquad bandpass (lowpass 3400 Hz -> highpass 300 Hz), torchaudio
// DF2T semantics with clamp [-1,1] after each stage (states use unclamped y).
// Time-parallel via truncated-IIR warmup: slowest pole |p|=0.9201, WU=128
// gives ~1e-3 absmax (measured R1), 7x under the 6.8e-3 threshold.
//
// R2: LCH=32 (LDS 19 KB -> 8 blocks/CU, 16 waves/CU) + chunked LDS layout
// (32 samples + 4 pad floats = 144 B stride, 16B aligned) so ALL LDS traffic
// is b128 with minimal phasing (no bank conflicts), including serial loops.

#define NT    128                // threads per block (2 waves)
#define LCH   32                 // output samples per thread
#define WUC   4                  // warmup chunks (4*32 = 128 samples)
#define CH_F4 9                  // float4 per chunk in LDS (8 data + 1 pad)
#define NCH   (NT + WUC)         // staged chunks per block = 132
#define SPAN  (NT * LCH)         // 4096 output samples per block
#define T_LEN 480000

__global__ __launch_bounds__(NT, 4)
void bandpass_kernel(const float* __restrict__ in, float* __restrict__ out,
                     float lb0, float lb1, float lb2, float nla1, float nla2,
                     float hb0, float hb1, float hb2, float nha1, float nha2) {
    __shared__ float4 lds4[NCH * CH_F4];   // 19008 B
    const int tid = threadIdx.x;
    const long tile_start = (long)blockIdx.x * SPAN;
    const float* __restrict__ src = in  + (long)blockIdx.y * T_LEN;
    float*       __restrict__ dst = out + (long)blockIdx.y * T_LEN;

    // ---- stage [tile_start-128, tile_start+SPAN) as float4, chunked layout
    const int NF4 = NCH * 8;     // 1056 data float4s
    for (int k = tid; k < NF4; k += NT) {
        long g = tile_start - 128 + 4L * k;   // sample index; always 16B aligned
        float4 v = make_float4(0.f, 0.f, 0.f, 0.f);
        if (g >= 0 && g + 4 <= T_LEN) v = *(const float4*)(src + g);
        lds4[CH_F4 * (k >> 3) + (k & 7)] = v;
    }
    __syncthreads();

    float s1a = 0.f, s2a = 0.f, s1b = 0.f, s2b = 0.f;

#define WSTEP(x) {                                         \
        float y1 = fmaf(lb0, (x), s1a);                    \
        s1a = fmaf(lb1, (x), fmaf(nla1, y1, s2a));         \
        s2a = fmaf(lb2, (x), nla2 * y1);                   \
        float x2 = fminf(fmaxf(y1, -1.f), 1.f);            \
        float y2 = fmaf(hb0, x2, s1b);                     \
        s1b = fmaf(hb1, x2, fmaf(nha1, y2, s2b));          \
        s2b = fmaf(hb2, x2, nha2 * y2);                    \
    }
#define OSTEP(x, o) {                                      \
        float y1 = fmaf(lb0, (x), s1a);                    \
        s1a = fmaf(lb1, (x), fmaf(nla1, y1, s2a));         \
        s2a = fmaf(lb2, (x), nla2 * y1);                   \
        float x2 = fminf(fmaxf(y1, -1.f), 1.f);            \
        float y2 = fmaf(hb0, x2, s1b);                     \
        s1b = fmaf(hb1, x2, fmaf(nha1, y2, s2b));          \
        s2b = fmaf(hb2, x2, nha2 * y2);                    \
        (o) = fminf(fmaxf(y2, -1.f), 1.f);                 \
    }

    // ---- warmup: staged chunks [tid, tid+WUC), 128 samples, b128 reads
    {
        const float4* wp = &lds4[CH_F4 * tid];
        for (int c = 0; c < WUC; ++c) {
            #pragma unroll
            for (int q = 0; q < 8; ++q) {
                float4 v = wp[CH_F4 * c + q];
                WSTEP(v.x); WSTEP(v.y); WSTEP(v.z); WSTEP(v.w);
            }
        }
    }
    __syncthreads();  // all cross-thread warmup reads done before in-place writes

    // ---- main: own chunk (tid+WUC), in-place overwrite, b128 read/write
    {
        float4* mp = &lds4[CH_F4 * (tid + WUC)];
        #pragma unroll
        for (int q = 0; q < 8; ++q) {
            float4 v = mp[q];
            float4 o;
            OSTEP(v.x, o.x); OSTEP(v.y, o.y); OSTEP(v.z, o.z); OSTEP(v.w, o.w);
            mp[q] = o;
        }
    }
    __syncthreads();

    // ---- coalesced writeback of SPAN outputs (skip WUC head chunks)
    for (int k = tid; k < SPAN / 4; k += NT) {
        long g = tile_start + 4L * k;
        if (g + 4 <= T_LEN) {   // T_LEN % 4 == 0 -> never partial
            *(float4*)(dst + g) = lds4[CH_F4 * ((k >> 3) + WUC) + (k & 7)];
        }
    }
#undef WSTEP
#undef OSTEP
}

static void biquad_coeffs(double cutoff, double sr, bool highpass, float* c) {
    const double Q  = 0.7071067811865476;
    const double w0 = 2.0 * M_PI * cutoff / sr;
    const double al = sin(w0) / (2.0 * Q);
    const double cw = cos(w0);
    double b0, b1, b2;
    if (highpass) { b0 = (1.0 + cw) / 2.0; b1 = -(1.0 + cw); b2 = b0; }
    else          { b0 = (1.0 - cw) / 2.0; b1 =  (1.0 - cw); b2 = b0; }
    const double a0 = 1.0 + al;
    const double a1 = -2.0 * cw;
    const double a2 = 1.0 - al;
    c[0] = (float)(b0 / a0);
    c[1] = (float)(b1 / a0);
    c[2] = (float)(b2 / a0);
    c[3] = (float)(-a1 / a0);   // pre-negated
    c[4] = (float)(-a2 / a0);   // pre-negated
}

extern "C" void kernel_launch(void* const* d_in, const int* in_sizes, int n_in,
                              void* d_out, int out_size, void* d_ws, size_t ws_size,
                              hipStream_t stream) {
    const float* in  = (const float*)d_in[0];
    float*       out = (float*)d_out;

    float lp[5], hp[5];
    biquad_coeffs(3400.0, 16000.0, false, lp);  // lowpass at max cutoff
    biquad_coeffs(300.0, 16000.0, true, hp);    // highpass at min cutoff

    const int n_seq  = in_sizes[0] / T_LEN;             // 64
    const int n_tile = (T_LEN + SPAN - 1) / SPAN;       // 118

    dim3 grid(n_tile, n_seq);
    bandpass_kernel<<<grid, NT, 0, stream>>>(
        in, out,
        lp[0], lp[1], lp[2], lp[3], lp[4],
        hp[0], hp[1], hp[2], hp[3], hp[4]);
}